// Round 1
// baseline (1358.559 us; speedup 1.0000x reference)
//
#include <hip/hip_runtime.h>
#include <cstdint>

#define NPTS 65536
#define NS 16
#define EPSV 1e-5f

// ---- stats/scratch layout (floats) within ws ----
#define SUM1 0
#define SSQ1 64
#define SUM2 128
#define SSQ2 192
#define SUM3 256
#define SSQ3 320
#define SC1  384
#define SH1  448
#define SC2  512
#define SH2  576
#define SC3  640
#define SH3  704
#define FLAGO 768
#define WKA_OFF 832
#define WQBA_OFF (832+4096)
#define BKA_OFF  (832+8192)
#define BQBA_OFF (832+8192+64)
#define STATS_FLOATS (832+8192+128)

// Detect knn_empty element width: if int32 bools, every word is 0/1.
// If uint8 bools, ~14% of words have a nonzero upper byte (value > 1).
__global__ void k_detect(const uint32_t* emp, float* stats) {
    __shared__ int cnt;
    if (threadIdx.x == 0) cnt = 0;
    __syncthreads();
    int bad = 0;
    for (int i = threadIdx.x; i < 1024; i += 256) {
        if (emp[i] > 1u) bad++;
    }
    atomicAdd(&cnt, bad);
    __syncthreads();
    if (threadIdx.x == 0) ((int*)stats)[FLAGO] = (cnt > 0) ? 1 : 0;  // 1 => uint8 layout
}

__global__ void k_mask(const void* emp, const float* stats, uint8_t* mask) {
    int i = blockIdx.x * 256 + threadIdx.x;
    int flag = ((const int*)stats)[FLAGO];
    uint8_t m;
    if (flag) m = (((const uint8_t*)emp)[i] != 0);
    else      m = (((const int*)emp)[i] != 0);
    mask[i] = m;
}

// Precompute folded weights: Wka = wk @ A_k, Wqba = wq @ (B-A)_k, plus biases.
// w1 is (134,64): A rows 0..66 (64 K-ch + 3 xyz), B rows 67..133.
__global__ void k0(const float* wq, const float* bq, const float* wk, const float* bk,
                   const float* w1, float* stats, int cin) {
    int f = threadIdx.x;   // 0..63
    int c = blockIdx.x;    // 0..cin-1
    float a = 0.f, q = 0.f;
    for (int d = 0; d < 64; d++) {
        float A  = w1[d*64 + f];
        float Bm = w1[(67+d)*64 + f] - A;
        a = fmaf(wk[c*64 + d], A,  a);
        q = fmaf(wq[c*64 + d], Bm, q);
    }
    stats[WKA_OFF  + c*64 + f] = a;
    stats[WQBA_OFF + c*64 + f] = q;
    if (c == 0) {
        float ba = 0.f, bqv = 0.f;
        for (int d = 0; d < 64; d++) {
            float A  = w1[d*64 + f];
            float Bm = w1[(67+d)*64 + f] - A;
            ba  = fmaf(bk[d], A,  ba);
            bqv = fmaf(bq[d], Bm, bqv);
        }
        stats[BKA_OFF  + f] = ba;
        stats[BQBA_OFF + f] = bqv;
    }
}

// KA[n,f] = bKA[f] + feats[n]@Wka[:,f] + xyz[n]@A_x[:,f]   (QBA analogous)
__global__ void k1(const float* feats, const float* xyz, const float* w1,
                   const float* stats, float* KA, float* QBA, int cin) {
    int t = blockIdx.x * 256 + threadIdx.x;
    int f = t & 63, n = t >> 6;
    const float* Wka  = stats + WKA_OFF;
    const float* Wqba = stats + WQBA_OFF;
    float ka = stats[BKA_OFF + f], qb = stats[BQBA_OFF + f];
    for (int c = 0; c < cin; c++) {
        float fv = feats[n*cin + c];
        ka = fmaf(fv, Wka[c*64 + f],  ka);
        qb = fmaf(fv, Wqba[c*64 + f], qb);
    }
    #pragma unroll
    for (int x = 0; x < 3; x++) {
        float xv = xyz[n*3 + x];
        float a  = w1[(64+x)*64 + f];
        ka = fmaf(xv, a, ka);
        qb = fmaf(xv, w1[(131+x)*64 + f] - a, qb);
    }
    KA[n*64 + f]  = ka;
    QBA[n*64 + f] = qb;
}

// Stats of y1 over (n,s): y1 = msk*(KA[idx]+QBA). Wave per point, lane = channel.
__global__ void k2(const float* KA, const float* QBA, const int* knn,
                   const uint8_t* mask, float* stats) {
    int lane = threadIdx.x & 63;
    int wv   = threadIdx.x >> 6;
    float s0 = 0.f, s1 = 0.f;
    for (int n = blockIdx.x * 4 + wv; n < NPTS; n += gridDim.x * 4) {
        float msk = mask[n] ? 0.0f : 1.0f;
        int myidx = knn[n*16 + (lane & 15)];
        float q = QBA[n*64 + lane];
        #pragma unroll
        for (int s = 0; s < 16; s++) {
            int j = __shfl(myidx, s, 64);
            float y = msk * (KA[j*64 + lane] + q);
            s0 += y;
            s1 = fmaf(y, y, s1);
        }
    }
    atomicAdd(&stats[SUM1 + lane], s0);
    atomicAdd(&stats[SSQ1 + lane], s1);
}

__global__ void kfin(const float* ssum, const float* sssq,
                     const float* g, const float* b, float* sc, float* sh, float cnt) {
    int f = threadIdx.x;
    float m = ssum[f] / cnt;
    float v = sssq[f] / cnt - m*m;
    v = fmaxf(v, 0.0f);
    float rs = rsqrtf(v + EPSV);
    float s = g[f] * rs;
    sc[f] = s;
    sh[f] = fmaf(-m, s, b[f]);
}

// Big kernel: recompute y1, bn1+relu -> x1 (lane=channel, 16 s in regs),
// einsum2 via readlane-broadcast matvec, accumulate stats2, store per-(n,f) max/min.
__global__ void __launch_bounds__(256) k4(const float* KA, const float* QBA, const int* knn,
                   const uint8_t* mask, const float* w2, float* stats,
                   float* y2max, float* y2min) {
    int lane = threadIdx.x & 63;
    int wv   = threadIdx.x >> 6;
    float w2c[64];
    #pragma unroll
    for (int c = 0; c < 64; c++) w2c[c] = w2[c*64 + lane];
    float sc1v = stats[SC1 + lane], sh1v = stats[SH1 + lane];
    float s0 = 0.f, s1 = 0.f;
    for (int n = blockIdx.x * 4 + wv; n < NPTS; n += gridDim.x * 4) {
        float msk = mask[n] ? 0.0f : 1.0f;
        int myidx = knn[n*16 + (lane & 15)];
        float q = QBA[n*64 + lane];
        float x1s[16];
        #pragma unroll
        for (int s = 0; s < 16; s++) {
            int j = __shfl(myidx, s, 64);
            float y = msk * (KA[j*64 + lane] + q);
            x1s[s] = fmaxf(fmaf(sc1v, y, sh1v), 0.0f);
        }
        float acc[16];
        #pragma unroll
        for (int s = 0; s < 16; s++) acc[s] = 0.0f;
        #pragma unroll
        for (int c = 0; c < 64; c++) {
            float wcc = w2c[c];
            #pragma unroll
            for (int s = 0; s < 16; s++) {
                float xc = __uint_as_float(__builtin_amdgcn_readlane(__float_as_uint(x1s[s]), c));
                acc[s] = fmaf(xc, wcc, acc[s]);
            }
        }
        float mx = -3.4e38f, mn = 3.4e38f;
        #pragma unroll
        for (int s = 0; s < 16; s++) {
            float y = acc[s];
            s0 += y;
            s1 = fmaf(y, y, s1);
            mx = fmaxf(mx, y);
            mn = fminf(mn, y);
        }
        y2max[n*64 + lane] = mx;
        y2min[n*64 + lane] = mn;
    }
    atomicAdd(&stats[SUM2 + lane], s0);
    atomicAdd(&stats[SSQ2 + lane], s1);
}

// m = relu(bn2(max/min per monotonicity)); y3 = m @ wo; stats3.
__global__ void k5(const float* y2max, const float* y2min, const float* wo,
                   float* stats, float* y3) {
    int lane = threadIdx.x & 63;
    int wv   = threadIdx.x >> 6;
    float woc[64];
    #pragma unroll
    for (int c = 0; c < 64; c++) woc[c] = wo[c*64 + lane];
    float sc2v = stats[SC2 + lane], sh2v = stats[SH2 + lane];
    float s0 = 0.f, s1 = 0.f;
    for (int n = blockIdx.x * 4 + wv; n < NPTS; n += gridDim.x * 4) {
        float pre = (sc2v >= 0.0f) ? y2max[n*64 + lane] : y2min[n*64 + lane];
        float m = fmaxf(fmaf(sc2v, pre, sh2v), 0.0f);
        float acc = 0.f;
        #pragma unroll
        for (int c = 0; c < 64; c++) {
            float xc = __uint_as_float(__builtin_amdgcn_readlane(__float_as_uint(m), c));
            acc = fmaf(xc, woc[c], acc);
        }
        y3[n*64 + lane] = acc;
        s0 += acc;
        s1 = fmaf(acc, acc, s1);
    }
    atomicAdd(&stats[SUM3 + lane], s0);
    atomicAdd(&stats[SSQ3 + lane], s1);
}

__global__ void k6(const float* y3, const float* stats, float* out) {
    int i = blockIdx.x * 256 + threadIdx.x;
    int f = i & 63;
    out[i] = fmaxf(fmaf(stats[SC3 + f], y3[i], stats[SH3 + f]), 0.0f);
}

extern "C" void kernel_launch(void* const* d_in, const int* in_sizes, int n_in,
                              void* d_out, int out_size, void* d_ws, size_t ws_size,
                              hipStream_t stream) {
    const float* xyz    = (const float*)d_in[0];
    const float* feats0 = (const float*)d_in[1];
    const int*   knn    = (const int*)d_in[2];
    const void*  empty  = d_in[3];
    float* ws = (float*)d_ws;
    const size_t N64 = (size_t)NPTS * 64;
    float* KA    = ws;
    float* QBA   = ws + N64;
    float* Y2MAX = ws + 2*N64;
    float* Y2MIN = ws + 3*N64;
    float* stats = ws + 4*N64;
    uint8_t* mask = (uint8_t*)(stats + STATS_FLOATS);
    float* out = (float*)d_out;

    k_detect<<<1, 256, 0, stream>>>((const uint32_t*)empty, stats);
    k_mask<<<NPTS/256, 256, 0, stream>>>(empty, stats, mask);

    const float* feats = feats0;
    int cin = 16;
    for (int L = 0; L < 2; L++) {
        const float* const* p = (const float* const*)(d_in + 4 + L*13);
        const float* wq = p[0];  const float* bq = p[1];
        const float* wk = p[2];  const float* bk = p[3];
        const float* w1 = p[4];  const float* g1 = p[5];  const float* b1 = p[6];
        const float* w2 = p[7];  const float* g2 = p[8];  const float* b2 = p[9];
        const float* wo = p[10]; const float* go = p[11]; const float* bo = p[12];

        hipMemsetAsync(stats, 0, 384 * sizeof(float), stream);
        k0<<<cin, 64, 0, stream>>>(wq, bq, wk, bk, w1, stats, cin);
        k1<<<NPTS*64/256, 256, 0, stream>>>(feats, xyz, w1, stats, KA, QBA, cin);
        k2<<<1024, 256, 0, stream>>>(KA, QBA, knn, mask, stats);
        kfin<<<1, 64, 0, stream>>>(stats+SUM1, stats+SSQ1, g1, b1, stats+SC1, stats+SH1,
                                   (float)((size_t)NPTS * NS));
        k4<<<2048, 256, 0, stream>>>(KA, QBA, knn, mask, w2, stats, Y2MAX, Y2MIN);
        kfin<<<1, 64, 0, stream>>>(stats+SUM2, stats+SSQ2, g2, b2, stats+SC2, stats+SH2,
                                   (float)((size_t)NPTS * NS));
        k5<<<1024, 256, 0, stream>>>(Y2MAX, Y2MIN, wo, stats, KA);   // y3 reuses KA
        kfin<<<1, 64, 0, stream>>>(stats+SUM3, stats+SSQ3, go, bo, stats+SC3, stats+SH3,
                                   (float)NPTS);
        k6<<<NPTS*64/256, 256, 0, stream>>>(KA, stats, out);

        feats = out;   // layer0 output feeds layer1; layer1 overwrites at the end
        cin = 64;
    }
}

// Round 2
// 653.027 us; speedup vs baseline: 2.0804x; 2.0804x over previous
//
#include <hip/hip_runtime.h>
#include <cstdint>

#define NPTS 65536
#define NS 16
#define EPSV 1e-5f

typedef __attribute__((ext_vector_type(8))) short bf16x8;
typedef __attribute__((ext_vector_type(4))) float f32x4;
typedef __attribute__((ext_vector_type(4))) unsigned int u32x4;
union FragU { u32x4 u; bf16x8 h; };

// ---- stats/scratch layout (floats) within ws ----
#define SUM1 0
#define SSQ1 64
#define SUM2 128
#define SSQ2 192
#define SUM3 256
#define SSQ3 320
#define WKA_OFF 832
#define WQBA_OFF (832+4096)
#define BKA_OFF  (832+8192)
#define BQBA_OFF (832+8192+64)
#define STATS_FLOATS (832+8192+128)

// split two floats into packed bf16 hi pair and lo pair (truncation both; hi+lo exact to ~2^-16)
__device__ __forceinline__ void split2(float e0, float e1, unsigned int& hi, unsigned int& lo) {
    unsigned int u0 = __float_as_uint(e0), u1 = __float_as_uint(e1);
    unsigned int h0 = u0 & 0xFFFF0000u, h1 = u1 & 0xFFFF0000u;
    hi = (h0 >> 16) | h1;
    float l0f = e0 - __uint_as_float(h0);
    float l1f = e1 - __uint_as_float(h1);
    lo = (__float_as_uint(l0f) >> 16) | (__float_as_uint(l1f) & 0xFFFF0000u);
}

// mask build + inline dtype detection (int32 bools are all 0/1; uint8 layout has words >1)
__global__ void k_mask(const uint32_t* emp32, uint8_t* mask) {
    int bad = 0;
    for (int w = threadIdx.x; w < 1024; w += 256) bad |= (emp32[w] > 1u) ? 1 : 0;
    __shared__ int sbad[4];
    unsigned long long b = __ballot(bad != 0);
    if ((threadIdx.x & 63) == 0) sbad[threadIdx.x >> 6] = (b != 0ull) ? 1 : 0;
    __syncthreads();
    int flag = sbad[0] | sbad[1] | sbad[2] | sbad[3];
    int i = blockIdx.x * 256 + threadIdx.x;
    uint8_t mv;
    if (flag) mv = (((const uint8_t*)emp32)[i] != 0);
    else      mv = (emp32[i] != 0u);
    mask[i] = mv;
}

// Folded weights: Wka = wk @ A, Wqba = wq @ (B-A); biases likewise. w1 (134,64): A rows 0..66, B rows 67..133.
__global__ void k0(const float* wq, const float* bq, const float* wk, const float* bk,
                   const float* w1, float* stats, int cin) {
    int f = threadIdx.x;
    int c = blockIdx.x;
    float a = 0.f, q = 0.f;
    for (int d = 0; d < 64; d++) {
        float A  = w1[d*64 + f];
        float Bm = w1[(67+d)*64 + f] - A;
        a = fmaf(wk[c*64 + d], A,  a);
        q = fmaf(wq[c*64 + d], Bm, q);
    }
    stats[WKA_OFF  + c*64 + f] = a;
    stats[WQBA_OFF + c*64 + f] = q;
    if (c == 0) {
        float ba = 0.f, bqv = 0.f;
        for (int d = 0; d < 64; d++) {
            float A  = w1[d*64 + f];
            float Bm = w1[(67+d)*64 + f] - A;
            ba  = fmaf(bk[d], A,  ba);
            bqv = fmaf(bq[d], Bm, bqv);
        }
        stats[BKA_OFF  + f] = ba;
        stats[BQBA_OFF + f] = bqv;
    }
}

// KA[n,f] = bKA[f] + feats[n]@Wka[:,f] + xyz[n]@A_x[:,f]; QBA analogous.
__global__ void k1(const float* feats, const float* xyz, const float* w1,
                   const float* stats, float* KA, float* QBA, int cin) {
    int t = blockIdx.x * 256 + threadIdx.x;
    int f = t & 63, n = t >> 6;
    const float* Wka  = stats + WKA_OFF;
    const float* Wqba = stats + WQBA_OFF;
    float ka = stats[BKA_OFF + f], qb = stats[BQBA_OFF + f];
    for (int c = 0; c < cin; c++) {
        float fv = feats[n*cin + c];
        ka = fmaf(fv, Wka[c*64 + f],  ka);
        qb = fmaf(fv, Wqba[c*64 + f], qb);
    }
    #pragma unroll
    for (int x = 0; x < 3; x++) {
        float xv = xyz[n*3 + x];
        float a  = w1[(64+x)*64 + f];
        ka = fmaf(xv, a, ka);
        qb = fmaf(xv, w1[(131+x)*64 + f] - a, qb);
    }
    KA[n*64 + f]  = ka;
    QBA[n*64 + f] = qb;
}

// Stats of y1 over (n,s): y1 = msk*(KA[idx]+QBA). Wave per point, lane = channel.
__global__ void k2(const float* KA, const float* QBA, const int* knn,
                   const uint8_t* mask, float* stats) {
    int lane = threadIdx.x & 63;
    int wv   = threadIdx.x >> 6;
    float s0 = 0.f, s1 = 0.f;
    for (int n = blockIdx.x * 4 + wv; n < NPTS; n += gridDim.x * 4) {
        float msk = mask[n] ? 0.0f : 1.0f;
        int myidx = knn[n*16 + (lane & 15)];
        float q = QBA[n*64 + lane];
        #pragma unroll
        for (int s = 0; s < 16; s++) {
            int j = __shfl(myidx, s, 64);
            float y = msk * (KA[j*64 + lane] + q);
            s0 += y;
            s1 = fmaf(y, y, s1);
        }
    }
    __shared__ float red[8][64];
    red[wv][lane] = s0;
    red[4+wv][lane] = s1;
    __syncthreads();
    if (wv == 0) {
        atomicAdd(&stats[SUM1 + lane], red[0][lane]+red[1][lane]+red[2][lane]+red[3][lane]);
        atomicAdd(&stats[SSQ1 + lane], red[4][lane]+red[5][lane]+red[6][lane]+red[7][lane]);
    }
}

// MFMA k4: recompute y1, bn1+relu -> x1 in A-fragment layout directly from gather,
// 3-term bf16 hi/lo split MFMA (fp32-equivalent), stats2 + per-(n,f) max/min of y2.
__global__ void __launch_bounds__(256) k4(const float* KA, const float* QBA, const int* knn,
                   const uint8_t* mask, const float* w2, const float* g1, const float* b1,
                   float* stats, float* y2max, float* y2min) {
    const int l    = threadIdx.x & 63;
    const int wv   = threadIdx.x >> 6;
    const int sidx = l & 15;       // s (A row / D col)
    const int g    = l >> 4;       // k-group
    const int col  = sidx;         // B col within f-tile

    // inline kfin1: per-lane bn1 scale/shift for channels c = t*32 + g*8 + i
    float sc1v[16], sh1v[16];
    const float inv = 1.0f / ((float)NPTS * (float)NS);
    #pragma unroll
    for (int t = 0; t < 2; t++)
    #pragma unroll
    for (int i = 0; i < 8; i++) {
        int c = t*32 + g*8 + i;
        float m = stats[SUM1 + c] * inv;
        float v = fmaxf(stats[SSQ1 + c] * inv - m*m, 0.0f);
        float s = g1[c] * rsqrtf(v + EPSV);
        sc1v[t*8+i] = s;
        sh1v[t*8+i] = fmaf(-m, s, b1[c]);
    }

    // w2 B-fragments, hi/lo split: frag[t][ft] covers k = t*32+g*8..+8, f = ft*16+col
    unsigned int whu[2][4][4], wlu[2][4][4];
    #pragma unroll
    for (int t = 0; t < 2; t++)
    #pragma unroll
    for (int ft = 0; ft < 4; ft++)
    #pragma unroll
    for (int r = 0; r < 4; r++) {
        int k0i = t*32 + g*8 + 2*r;
        float e0 = w2[k0i*64 + ft*16 + col];
        float e1 = w2[(k0i+1)*64 + ft*16 + col];
        split2(e0, e1, whu[t][ft][r], wlu[t][ft][r]);
    }

    float s0t[4] = {0.f,0.f,0.f,0.f};
    float s1t[4] = {0.f,0.f,0.f,0.f};

    for (int n = blockIdx.x * 4 + wv; n < NPTS; n += gridDim.x * 4) {
        bool masked = mask[n] != 0;
        int j = knn[n*16 + sidx];

        // gather A-fragment source: KA row j, chunks (t*32 + g*8)
        f32x4 kaA = *(const f32x4*)(KA + j*64 + g*8);
        f32x4 kaB = *(const f32x4*)(KA + j*64 + g*8 + 4);
        f32x4 kaC = *(const f32x4*)(KA + j*64 + 32 + g*8);
        f32x4 kaD = *(const f32x4*)(KA + j*64 + 32 + g*8 + 4);
        f32x4 qA  = *(const f32x4*)(QBA + n*64 + g*8);
        f32x4 qB  = *(const f32x4*)(QBA + n*64 + g*8 + 4);
        f32x4 qC  = *(const f32x4*)(QBA + n*64 + 32 + g*8);
        f32x4 qD  = *(const f32x4*)(QBA + n*64 + 32 + g*8 + 4);

        float x[16];
        #pragma unroll
        for (int i = 0; i < 4; i++) {
            float y0 = masked ? 0.f : (kaA[i] + qA[i]);
            float y1 = masked ? 0.f : (kaB[i] + qB[i]);
            float y2 = masked ? 0.f : (kaC[i] + qC[i]);
            float y3 = masked ? 0.f : (kaD[i] + qD[i]);
            x[i]    = fmaxf(fmaf(sc1v[i],    y0, sh1v[i]),    0.0f);
            x[4+i]  = fmaxf(fmaf(sc1v[4+i],  y1, sh1v[4+i]),  0.0f);
            x[8+i]  = fmaxf(fmaf(sc1v[8+i],  y2, sh1v[8+i]),  0.0f);
            x[12+i] = fmaxf(fmaf(sc1v[12+i], y3, sh1v[12+i]), 0.0f);
        }

        // split/pack A fragments
        unsigned int ahu[2][4], alu[2][4];
        #pragma unroll
        for (int t = 0; t < 2; t++)
        #pragma unroll
        for (int r = 0; r < 4; r++)
            split2(x[t*8 + 2*r], x[t*8 + 2*r + 1], ahu[t][r], alu[t][r]);

        f32x4 acc[4];
        #pragma unroll
        for (int ft = 0; ft < 4; ft++) acc[ft] = (f32x4){0.f,0.f,0.f,0.f};

        #pragma unroll
        for (int t = 0; t < 2; t++) {
            FragU ah, al;
            ah.u = (u32x4){ahu[t][0], ahu[t][1], ahu[t][2], ahu[t][3]};
            al.u = (u32x4){alu[t][0], alu[t][1], alu[t][2], alu[t][3]};
            #pragma unroll
            for (int ft = 0; ft < 4; ft++) {
                FragU bh, bl;
                bh.u = (u32x4){whu[t][ft][0], whu[t][ft][1], whu[t][ft][2], whu[t][ft][3]};
                bl.u = (u32x4){wlu[t][ft][0], wlu[t][ft][1], wlu[t][ft][2], wlu[t][ft][3]};
                acc[ft] = __builtin_amdgcn_mfma_f32_16x16x32_bf16(ah.h, bh.h, acc[ft], 0, 0, 0);
                acc[ft] = __builtin_amdgcn_mfma_f32_16x16x32_bf16(ah.h, bl.h, acc[ft], 0, 0, 0);
                acc[ft] = __builtin_amdgcn_mfma_f32_16x16x32_bf16(al.h, bh.h, acc[ft], 0, 0, 0);
            }
        }

        // epilogue: stats + max/min over s.  D: lane holds y2[s=g*4+r][f=ft*16+col]
        float tmax[4], tmin[4];
        #pragma unroll
        for (int ft = 0; ft < 4; ft++) {
            f32x4 d = acc[ft];
            float lmax = fmaxf(fmaxf(d[0], d[1]), fmaxf(d[2], d[3]));
            float lmin = fminf(fminf(d[0], d[1]), fminf(d[2], d[3]));
            s0t[ft] += (d[0] + d[1]) + (d[2] + d[3]);
            s1t[ft] += fmaf(d[0],d[0], fmaf(d[1],d[1], fmaf(d[2],d[2], d[3]*d[3])));
            lmax = fmaxf(lmax, __shfl_xor(lmax, 16, 64));
            lmax = fmaxf(lmax, __shfl_xor(lmax, 32, 64));
            lmin = fminf(lmin, __shfl_xor(lmin, 16, 64));
            lmin = fminf(lmin, __shfl_xor(lmin, 32, 64));
            tmax[ft] = lmax; tmin[ft] = lmin;
        }
        float mx = (g==0) ? tmax[0] : (g==1) ? tmax[1] : (g==2) ? tmax[2] : tmax[3];
        float mn = (g==0) ? tmin[0] : (g==1) ? tmin[1] : (g==2) ? tmin[2] : tmin[3];
        y2max[n*64 + l] = mx;   // lane l == f for its tile
        y2min[n*64 + l] = mn;
    }

    // stats reduce: cross-g sum, then lane l owns f=l (tile g)
    #pragma unroll
    for (int ft = 0; ft < 4; ft++) {
        s0t[ft] += __shfl_xor(s0t[ft], 16, 64);
        s0t[ft] += __shfl_xor(s0t[ft], 32, 64);
        s1t[ft] += __shfl_xor(s1t[ft], 16, 64);
        s1t[ft] += __shfl_xor(s1t[ft], 32, 64);
    }
    float myS0 = (g==0) ? s0t[0] : (g==1) ? s0t[1] : (g==2) ? s0t[2] : s0t[3];
    float myS1 = (g==0) ? s1t[0] : (g==1) ? s1t[1] : (g==2) ? s1t[2] : s1t[3];
    __shared__ float red[8][64];
    red[wv][l] = myS0;
    red[4+wv][l] = myS1;
    __syncthreads();
    if (wv == 0) {
        atomicAdd(&stats[SUM2 + l], red[0][l]+red[1][l]+red[2][l]+red[3][l]);
        atomicAdd(&stats[SSQ2 + l], red[4][l]+red[5][l]+red[6][l]+red[7][l]);
    }
}

// m = relu(bn2(max/min per monotonicity)); y3 = m @ wo; stats3. Inline kfin2.
__global__ void k5(const float* y2max, const float* y2min, const float* wo,
                   const float* g2, const float* b2, float* stats, float* y3) {
    int lane = threadIdx.x & 63;
    int wv   = threadIdx.x >> 6;
    float woc[64];
    #pragma unroll
    for (int c = 0; c < 64; c++) woc[c] = wo[c*64 + lane];
    const float inv = 1.0f / ((float)NPTS * (float)NS);
    float m2 = stats[SUM2 + lane] * inv;
    float v2 = fmaxf(stats[SSQ2 + lane] * inv - m2*m2, 0.0f);
    float sc2 = g2[lane] * rsqrtf(v2 + EPSV);
    float sh2 = fmaf(-m2, sc2, b2[lane]);
    float s0 = 0.f, s1 = 0.f;
    for (int n = blockIdx.x * 4 + wv; n < NPTS; n += gridDim.x * 4) {
        float pre = (sc2 >= 0.0f) ? y2max[n*64 + lane] : y2min[n*64 + lane];
        float m = fmaxf(fmaf(sc2, pre, sh2), 0.0f);
        float acc = 0.f;
        #pragma unroll
        for (int c = 0; c < 64; c++) {
            float xc = __uint_as_float(__builtin_amdgcn_readlane(__float_as_uint(m), c));
            acc = fmaf(xc, woc[c], acc);
        }
        y3[n*64 + lane] = acc;
        s0 += acc;
        s1 = fmaf(acc, acc, s1);
    }
    __shared__ float red[8][64];
    red[wv][lane] = s0;
    red[4+wv][lane] = s1;
    __syncthreads();
    if (wv == 0) {
        atomicAdd(&stats[SUM3 + lane], red[0][lane]+red[1][lane]+red[2][lane]+red[3][lane]);
        atomicAdd(&stats[SSQ3 + lane], red[4][lane]+red[5][lane]+red[6][lane]+red[7][lane]);
    }
}

// out = relu(bn3(y3)) with inline kfin3 (cnt = N).
__global__ void k6(const float* y3, const float* stats, const float* go, const float* bo,
                   float* out) {
    int i = blockIdx.x * 256 + threadIdx.x;
    int f = i & 63;
    const float inv = 1.0f / (float)NPTS;
    float m = stats[SUM3 + f] * inv;
    float v = fmaxf(stats[SSQ3 + f] * inv - m*m, 0.0f);
    float s = go[f] * rsqrtf(v + EPSV);
    float sh = fmaf(-m, s, bo[f]);
    out[i] = fmaxf(fmaf(s, y3[i], sh), 0.0f);
}

extern "C" void kernel_launch(void* const* d_in, const int* in_sizes, int n_in,
                              void* d_out, int out_size, void* d_ws, size_t ws_size,
                              hipStream_t stream) {
    const float* xyz    = (const float*)d_in[0];
    const float* feats0 = (const float*)d_in[1];
    const int*   knn    = (const int*)d_in[2];
    const void*  empty  = d_in[3];
    float* ws = (float*)d_ws;
    const size_t N64 = (size_t)NPTS * 64;
    float* KA    = ws;
    float* QBA   = ws + N64;
    float* Y2MAX = ws + 2*N64;
    float* Y2MIN = ws + 3*N64;
    float* stats = ws + 4*N64;
    uint8_t* mask = (uint8_t*)(stats + STATS_FLOATS);
    float* out = (float*)d_out;

    k_mask<<<NPTS/256, 256, 0, stream>>>((const uint32_t*)empty, mask);

    const float* feats = feats0;
    int cin = 16;
    for (int L = 0; L < 2; L++) {
        const float* const* p = (const float* const*)(d_in + 4 + L*13);
        const float* wq = p[0];  const float* bq = p[1];
        const float* wk = p[2];  const float* bk = p[3];
        const float* w1 = p[4];  const float* g1 = p[5];  const float* b1 = p[6];
        const float* w2 = p[7];  const float* g2 = p[8];  const float* b2 = p[9];
        const float* wo = p[10]; const float* go = p[11]; const float* bo = p[12];

        hipMemsetAsync(stats, 0, 384 * sizeof(float), stream);
        k0<<<cin, 64, 0, stream>>>(wq, bq, wk, bk, w1, stats, cin);
        k1<<<NPTS*64/256, 256, 0, stream>>>(feats, xyz, w1, stats, KA, QBA, cin);
        k2<<<1024, 256, 0, stream>>>(KA, QBA, knn, mask, stats);
        k4<<<1024, 256, 0, stream>>>(KA, QBA, knn, mask, w2, g1, b1, stats, Y2MAX, Y2MIN);
        k5<<<1024, 256, 0, stream>>>(Y2MAX, Y2MIN, wo, g2, b2, stats, KA);  // y3 reuses KA
        k6<<<NPTS*64/256, 256, 0, stream>>>(KA, stats, go, bo, out);

        feats = out;
        cin = 64;
    }
}

// Round 3
// 621.286 us; speedup vs baseline: 2.1867x; 1.0511x over previous
//
#include <hip/hip_runtime.h>
#include <cstdint>

#define NPTS 65536
#define NS 16
#define EPSV 1e-5f

typedef __attribute__((ext_vector_type(8))) short bf16x8;
typedef __attribute__((ext_vector_type(4))) float f32x4;
typedef __attribute__((ext_vector_type(4))) unsigned int u32x4;
union FragU { u32x4 u; bf16x8 h; };

// per-layer stats block (512 floats each)
#define SUM1 0
#define SSQ1 64
#define SUM2 128
#define SSQ2 192
#define SUM3 256
#define SSQ3 320
// wfold region (floats)
#define WKAOF 0
#define WQBAOF 4096
#define BKAOF 8192
#define BQBAOF 8256
#define WFOLD_FLOATS 8320

__device__ __forceinline__ void split2(float e0, float e1, unsigned int& hi, unsigned int& lo) {
    unsigned int u0 = __float_as_uint(e0), u1 = __float_as_uint(e1);
    unsigned int h0 = u0 & 0xFFFF0000u, h1 = u1 & 0xFFFF0000u;
    hi = (h0 >> 16) | h1;
    float l0f = e0 - __uint_as_float(h0);
    float l1f = e1 - __uint_as_float(h1);
    lo = (__float_as_uint(l0f) >> 16) | (__float_as_uint(l1f) & 0xFFFF0000u);
}

__global__ void k_mask(const uint32_t* emp32, uint8_t* mask) {
    int bad = 0;
    for (int w = threadIdx.x; w < 1024; w += 256) bad |= (emp32[w] > 1u) ? 1 : 0;
    __shared__ int sbad[4];
    unsigned long long b = __ballot(bad != 0);
    if ((threadIdx.x & 63) == 0) sbad[threadIdx.x >> 6] = (b != 0ull) ? 1 : 0;
    __syncthreads();
    int flag = sbad[0] | sbad[1] | sbad[2] | sbad[3];
    int i = blockIdx.x * 256 + threadIdx.x;
    uint8_t mv;
    if (flag) mv = (((const uint8_t*)emp32)[i] != 0);
    else      mv = (emp32[i] != 0u);
    mask[i] = mv;
}

// Folded weights: Wka = wk @ A, Wqba = wq @ (B-A); biases likewise.
__global__ void k0(const float* wq, const float* bq, const float* wk, const float* bk,
                   const float* w1, float* wfold, int cin) {
    int f = threadIdx.x;
    int c = blockIdx.x;
    float a = 0.f, q = 0.f;
    for (int d = 0; d < 64; d++) {
        float A  = w1[d*64 + f];
        float Bm = w1[(67+d)*64 + f] - A;
        a = fmaf(wk[c*64 + d], A,  a);
        q = fmaf(wq[c*64 + d], Bm, q);
    }
    wfold[WKAOF  + c*64 + f] = a;
    wfold[WQBAOF + c*64 + f] = q;
    if (c == 0) {
        float ba = 0.f, bqv = 0.f;
        for (int d = 0; d < 64; d++) {
            float A  = w1[d*64 + f];
            float Bm = w1[(67+d)*64 + f] - A;
            ba  = fmaf(bk[d], A,  ba);
            bqv = fmaf(bq[d], Bm, bqv);
        }
        wfold[BKAOF  + f] = ba;
        wfold[BQBAOF + f] = bqv;
    }
}

// MFMA k1: [KA|QBA](n,128) = prebn(feats) @ Wcat(cin,128) + xyz @ Axyz(3,128) + bias.
// Wave wv covers f-tiles (wv*2, wv*2+1); 16 points per tile; bias in C-init.
template<int CIN, bool PREBN>
__global__ void __launch_bounds__(256) k1m(const float* __restrict__ feats, const float* __restrict__ xyz,
                    const float* __restrict__ w1, const float* __restrict__ wfold,
                    const float* __restrict__ statsPrev, const float* __restrict__ goP,
                    const float* __restrict__ boP,
                    float* __restrict__ KA, float* __restrict__ QBA) {
    const int l = threadIdx.x & 63;
    const int wv = threadIdx.x >> 6;
    const int sidx = l & 15;
    const int g = l >> 4;
    const int col = sidx;
    constexpr int NT = (CIN == 64) ? 2 : 1;

    // B fragments for feats K-steps
    unsigned int bh[NT][2][4], bl[NT][2][4];
    #pragma unroll
    for (int t = 0; t < NT; t++)
    #pragma unroll
    for (int fl = 0; fl < 2; fl++) {
        int f128 = (wv*2 + fl)*16 + col;
        const float* W = (f128 < 64) ? (wfold + WKAOF) : (wfold + WQBAOF);
        int f = (f128 < 64) ? f128 : f128 - 64;
        #pragma unroll
        for (int r = 0; r < 4; r++) {
            int c0 = t*32 + g*8 + 2*r;
            float e0 = 0.f, e1 = 0.f;
            if (CIN == 64 || g < 2) {
                e0 = W[c0*64 + f];
                e1 = W[(c0+1)*64 + f];
            }
            split2(e0, e1, bh[t][fl][r], bl[t][fl][r]);
        }
    }
    // xyz B fragment (rows 0..2) + bias
    unsigned int xbh[2][4], xbl[2][4];
    float biasf[2];
    #pragma unroll
    for (int fl = 0; fl < 2; fl++) {
        int f128 = (wv*2 + fl)*16 + col;
        float A0, A1, A2;
        if (f128 < 64) {
            A0 = w1[64*64 + f128]; A1 = w1[65*64 + f128]; A2 = w1[66*64 + f128];
            biasf[fl] = wfold[BKAOF + f128];
        } else {
            int f = f128 - 64;
            A0 = w1[131*64 + f] - w1[64*64 + f];
            A1 = w1[132*64 + f] - w1[65*64 + f];
            A2 = w1[133*64 + f] - w1[66*64 + f];
            biasf[fl] = wfold[BQBAOF + f];
        }
        split2(A0, A1, xbh[fl][0], xbl[fl][0]);
        split2(A2, 0.f, xbh[fl][1], xbl[fl][1]);
        xbh[fl][2] = 0; xbh[fl][3] = 0; xbl[fl][2] = 0; xbl[fl][3] = 0;
    }
    // PREBN constants (layer-0 bn3): channels c = t*32 + g*8 + i
    float scP[NT*8], shP[NT*8];
    if (PREBN) {
        const float invN = 1.0f / (float)NPTS;
        #pragma unroll
        for (int t = 0; t < NT; t++)
        #pragma unroll
        for (int i = 0; i < 8; i++) {
            int c = t*32 + g*8 + i;
            float m = statsPrev[SUM3 + c] * invN;
            float v = fmaxf(statsPrev[SSQ3 + c] * invN - m*m, 0.0f);
            float s = goP[c] * rsqrtf(v + EPSV);
            scP[t*8+i] = s;
            shP[t*8+i] = fmaf(-m, s, boP[c]);
        }
    }

    for (int tile = blockIdx.x; tile < NPTS/16; tile += gridDim.x) {
        int p = tile*16 + sidx;
        unsigned int ahu[NT][4], alu[NT][4];
        #pragma unroll
        for (int t = 0; t < NT; t++) {
            float xv[8];
            if (CIN == 64) {
                f32x4 a0 = *(const f32x4*)(feats + (size_t)p*64 + t*32 + g*8);
                f32x4 a1 = *(const f32x4*)(feats + (size_t)p*64 + t*32 + g*8 + 4);
                #pragma unroll
                for (int i = 0; i < 4; i++) { xv[i] = a0[i]; xv[4+i] = a1[i]; }
                if (PREBN) {
                    #pragma unroll
                    for (int i = 0; i < 8; i++)
                        xv[i] = fmaxf(fmaf(scP[t*8+i], xv[i], shP[t*8+i]), 0.0f);
                }
            } else {
                if (g < 2) {
                    f32x4 a0 = *(const f32x4*)(feats + (size_t)p*16 + g*8);
                    f32x4 a1 = *(const f32x4*)(feats + (size_t)p*16 + g*8 + 4);
                    #pragma unroll
                    for (int i = 0; i < 4; i++) { xv[i] = a0[i]; xv[4+i] = a1[i]; }
                } else {
                    #pragma unroll
                    for (int i = 0; i < 8; i++) xv[i] = 0.f;
                }
            }
            #pragma unroll
            for (int r = 0; r < 4; r++) split2(xv[2*r], xv[2*r+1], ahu[t][r], alu[t][r]);
        }
        unsigned int xah[4] = {0,0,0,0}, xal[4] = {0,0,0,0};
        if (g == 0) {
            float x0 = xyz[p*3], x1 = xyz[p*3+1], x2 = xyz[p*3+2];
            split2(x0, x1, xah[0], xal[0]);
            split2(x2, 0.f, xah[1], xal[1]);
        }
        f32x4 acc[2];
        #pragma unroll
        for (int fl = 0; fl < 2; fl++)
            acc[fl] = (f32x4){biasf[fl], biasf[fl], biasf[fl], biasf[fl]};
        #pragma unroll
        for (int t = 0; t < NT; t++) {
            FragU ah, al;
            ah.u = (u32x4){ahu[t][0], ahu[t][1], ahu[t][2], ahu[t][3]};
            al.u = (u32x4){alu[t][0], alu[t][1], alu[t][2], alu[t][3]};
            #pragma unroll
            for (int fl = 0; fl < 2; fl++) {
                FragU Bh, Bl;
                Bh.u = (u32x4){bh[t][fl][0], bh[t][fl][1], bh[t][fl][2], bh[t][fl][3]};
                Bl.u = (u32x4){bl[t][fl][0], bl[t][fl][1], bl[t][fl][2], bl[t][fl][3]};
                acc[fl] = __builtin_amdgcn_mfma_f32_16x16x32_bf16(ah.h, Bh.h, acc[fl], 0, 0, 0);
                acc[fl] = __builtin_amdgcn_mfma_f32_16x16x32_bf16(ah.h, Bl.h, acc[fl], 0, 0, 0);
                acc[fl] = __builtin_amdgcn_mfma_f32_16x16x32_bf16(al.h, Bh.h, acc[fl], 0, 0, 0);
            }
        }
        {
            FragU ah, al;
            ah.u = (u32x4){xah[0], xah[1], xah[2], xah[3]};
            al.u = (u32x4){xal[0], xal[1], xal[2], xal[3]};
            #pragma unroll
            for (int fl = 0; fl < 2; fl++) {
                FragU Bh, Bl;
                Bh.u = (u32x4){xbh[fl][0], xbh[fl][1], xbh[fl][2], xbh[fl][3]};
                Bl.u = (u32x4){xbl[fl][0], xbl[fl][1], xbl[fl][2], xbl[fl][3]};
                acc[fl] = __builtin_amdgcn_mfma_f32_16x16x32_bf16(ah.h, Bh.h, acc[fl], 0, 0, 0);
                acc[fl] = __builtin_amdgcn_mfma_f32_16x16x32_bf16(ah.h, Bl.h, acc[fl], 0, 0, 0);
                acc[fl] = __builtin_amdgcn_mfma_f32_16x16x32_bf16(al.h, Bh.h, acc[fl], 0, 0, 0);
            }
        }
        #pragma unroll
        for (int fl = 0; fl < 2; fl++) {
            int f128 = (wv*2 + fl)*16 + col;
            #pragma unroll
            for (int r = 0; r < 4; r++) {
                int po = tile*16 + g*4 + r;
                float v = acc[fl][r];
                if (f128 < 64) KA[(size_t)po*64 + f128] = v;
                else           QBA[(size_t)po*64 + (f128-64)] = v;
            }
        }
    }
}

// Stats of y1 over (n,s): vectorized f32x4 gather. lane = (g, s).
__global__ void __launch_bounds__(256) k2(const float* __restrict__ KA, const float* __restrict__ QBA,
                   const int* __restrict__ knn, const uint8_t* __restrict__ mask, float* stats) {
    const int l = threadIdx.x & 63;
    const int wv = threadIdx.x >> 6;
    const int s = l & 15;
    const int g = l >> 4;
    float s0[16], s1[16];
    #pragma unroll
    for (int i = 0; i < 16; i++) { s0[i] = 0.f; s1[i] = 0.f; }
    for (int n = blockIdx.x * 4 + wv; n < NPTS; n += gridDim.x * 4) {
        if (mask[n]) continue;
        int j = knn[n*16 + s];
        const float* kap = KA + (size_t)j*64 + g*16;
        const float* qbp = QBA + (size_t)n*64 + g*16;
        #pragma unroll
        for (int q = 0; q < 4; q++) {
            f32x4 ka = *(const f32x4*)(kap + q*4);
            f32x4 qb = *(const f32x4*)(qbp + q*4);
            #pragma unroll
            for (int e = 0; e < 4; e++) {
                float y = ka[e] + qb[e];
                s0[q*4+e] += y;
                s1[q*4+e] = fmaf(y, y, s1[q*4+e]);
            }
        }
    }
    #pragma unroll
    for (int i = 0; i < 16; i++) {
        #pragma unroll
        for (int d = 1; d < 16; d <<= 1) {
            s0[i] += __shfl_xor(s0[i], d, 64);
            s1[i] += __shfl_xor(s1[i], d, 64);
        }
    }
    __shared__ float r0[4][64], r1[4][64];
    if (s == 0) {
        #pragma unroll
        for (int i = 0; i < 16; i++) { r0[wv][g*16+i] = s0[i]; r1[wv][g*16+i] = s1[i]; }
    }
    __syncthreads();
    int tid = threadIdx.x;
    if (tid < 64) {
        atomicAdd(&stats[SUM1 + tid], r0[0][tid]+r0[1][tid]+r0[2][tid]+r0[3][tid]);
        atomicAdd(&stats[SSQ1 + tid], r1[0][tid]+r1[1][tid]+r1[2][tid]+r1[3][tid]);
    }
}

// MFMA k4: gather -> bn1+relu -> x1 @ w2 (3-term split), stats2 + per-(n,f) max/min.
__global__ void __launch_bounds__(256) k4(const float* KA, const float* QBA, const int* knn,
                   const uint8_t* mask, const float* w2, const float* g1, const float* b1,
                   float* stats, float* y2max, float* y2min) {
    const int l    = threadIdx.x & 63;
    const int wv   = threadIdx.x >> 6;
    const int sidx = l & 15;
    const int g    = l >> 4;
    const int col  = sidx;

    float sc1v[16], sh1v[16];
    const float inv = 1.0f / ((float)NPTS * (float)NS);
    #pragma unroll
    for (int t = 0; t < 2; t++)
    #pragma unroll
    for (int i = 0; i < 8; i++) {
        int c = t*32 + g*8 + i;
        float m = stats[SUM1 + c] * inv;
        float v = fmaxf(stats[SSQ1 + c] * inv - m*m, 0.0f);
        float s = g1[c] * rsqrtf(v + EPSV);
        sc1v[t*8+i] = s;
        sh1v[t*8+i] = fmaf(-m, s, b1[c]);
    }

    unsigned int whu[2][4][4], wlu[2][4][4];
    #pragma unroll
    for (int t = 0; t < 2; t++)
    #pragma unroll
    for (int ft = 0; ft < 4; ft++)
    #pragma unroll
    for (int r = 0; r < 4; r++) {
        int k0i = t*32 + g*8 + 2*r;
        float e0 = w2[k0i*64 + ft*16 + col];
        float e1 = w2[(k0i+1)*64 + ft*16 + col];
        split2(e0, e1, whu[t][ft][r], wlu[t][ft][r]);
    }

    float s0t[4] = {0.f,0.f,0.f,0.f};
    float s1t[4] = {0.f,0.f,0.f,0.f};

    for (int n = blockIdx.x * 4 + wv; n < NPTS; n += gridDim.x * 4) {
        bool masked = mask[n] != 0;
        int j = knn[n*16 + sidx];

        f32x4 kaA = *(const f32x4*)(KA + (size_t)j*64 + g*8);
        f32x4 kaB = *(const f32x4*)(KA + (size_t)j*64 + g*8 + 4);
        f32x4 kaC = *(const f32x4*)(KA + (size_t)j*64 + 32 + g*8);
        f32x4 kaD = *(const f32x4*)(KA + (size_t)j*64 + 32 + g*8 + 4);
        f32x4 qA  = *(const f32x4*)(QBA + (size_t)n*64 + g*8);
        f32x4 qB  = *(const f32x4*)(QBA + (size_t)n*64 + g*8 + 4);
        f32x4 qC  = *(const f32x4*)(QBA + (size_t)n*64 + 32 + g*8);
        f32x4 qD  = *(const f32x4*)(QBA + (size_t)n*64 + 32 + g*8 + 4);

        float x[16];
        #pragma unroll
        for (int i = 0; i < 4; i++) {
            float y0 = masked ? 0.f : (kaA[i] + qA[i]);
            float y1 = masked ? 0.f : (kaB[i] + qB[i]);
            float y2 = masked ? 0.f : (kaC[i] + qC[i]);
            float y3 = masked ? 0.f : (kaD[i] + qD[i]);
            x[i]    = fmaxf(fmaf(sc1v[i],    y0, sh1v[i]),    0.0f);
            x[4+i]  = fmaxf(fmaf(sc1v[4+i],  y1, sh1v[4+i]),  0.0f);
            x[8+i]  = fmaxf(fmaf(sc1v[8+i],  y2, sh1v[8+i]),  0.0f);
            x[12+i] = fmaxf(fmaf(sc1v[12+i], y3, sh1v[12+i]), 0.0f);
        }

        unsigned int ahu[2][4], alu[2][4];
        #pragma unroll
        for (int t = 0; t < 2; t++)
        #pragma unroll
        for (int r = 0; r < 4; r++)
            split2(x[t*8 + 2*r], x[t*8 + 2*r + 1], ahu[t][r], alu[t][r]);

        f32x4 acc[4];
        #pragma unroll
        for (int ft = 0; ft < 4; ft++) acc[ft] = (f32x4){0.f,0.f,0.f,0.f};

        #pragma unroll
        for (int t = 0; t < 2; t++) {
            FragU ah, al;
            ah.u = (u32x4){ahu[t][0], ahu[t][1], ahu[t][2], ahu[t][3]};
            al.u = (u32x4){alu[t][0], alu[t][1], alu[t][2], alu[t][3]};
            #pragma unroll
            for (int ft = 0; ft < 4; ft++) {
                FragU bhf, blf;
                bhf.u = (u32x4){whu[t][ft][0], whu[t][ft][1], whu[t][ft][2], whu[t][ft][3]};
                blf.u = (u32x4){wlu[t][ft][0], wlu[t][ft][1], wlu[t][ft][2], wlu[t][ft][3]};
                acc[ft] = __builtin_amdgcn_mfma_f32_16x16x32_bf16(ah.h, bhf.h, acc[ft], 0, 0, 0);
                acc[ft] = __builtin_amdgcn_mfma_f32_16x16x32_bf16(ah.h, blf.h, acc[ft], 0, 0, 0);
                acc[ft] = __builtin_amdgcn_mfma_f32_16x16x32_bf16(al.h, bhf.h, acc[ft], 0, 0, 0);
            }
        }

        float tmax[4], tmin[4];
        #pragma unroll
        for (int ft = 0; ft < 4; ft++) {
            f32x4 d = acc[ft];
            float lmax = fmaxf(fmaxf(d[0], d[1]), fmaxf(d[2], d[3]));
            float lmin = fminf(fminf(d[0], d[1]), fminf(d[2], d[3]));
            s0t[ft] += (d[0] + d[1]) + (d[2] + d[3]);
            s1t[ft] += fmaf(d[0],d[0], fmaf(d[1],d[1], fmaf(d[2],d[2], d[3]*d[3])));
            lmax = fmaxf(lmax, __shfl_xor(lmax, 16, 64));
            lmax = fmaxf(lmax, __shfl_xor(lmax, 32, 64));
            lmin = fminf(lmin, __shfl_xor(lmin, 16, 64));
            lmin = fminf(lmin, __shfl_xor(lmin, 32, 64));
            tmax[ft] = lmax; tmin[ft] = lmin;
        }
        float mx = (g==0) ? tmax[0] : (g==1) ? tmax[1] : (g==2) ? tmax[2] : tmax[3];
        float mn = (g==0) ? tmin[0] : (g==1) ? tmin[1] : (g==2) ? tmin[2] : tmin[3];
        y2max[(size_t)n*64 + l] = mx;
        y2min[(size_t)n*64 + l] = mn;
    }

    #pragma unroll
    for (int ft = 0; ft < 4; ft++) {
        s0t[ft] += __shfl_xor(s0t[ft], 16, 64);
        s0t[ft] += __shfl_xor(s0t[ft], 32, 64);
        s1t[ft] += __shfl_xor(s1t[ft], 16, 64);
        s1t[ft] += __shfl_xor(s1t[ft], 32, 64);
    }
    float myS0 = (g==0) ? s0t[0] : (g==1) ? s0t[1] : (g==2) ? s0t[2] : s0t[3];
    float myS1 = (g==0) ? s1t[0] : (g==1) ? s1t[1] : (g==2) ? s1t[2] : s1t[3];
    __shared__ float red[8][64];
    red[wv][l] = myS0;
    red[4+wv][l] = myS1;
    __syncthreads();
    if (wv == 0) {
        atomicAdd(&stats[SUM2 + l], red[0][l]+red[1][l]+red[2][l]+red[3][l]);
        atomicAdd(&stats[SSQ2 + l], red[4][l]+red[5][l]+red[6][l]+red[7][l]);
    }
}

// MFMA k5: m = relu(bn2(max/min)); y3 = m @ wo; stats3. Wave wv = f-tile.
__global__ void __launch_bounds__(256) k5m(const float* __restrict__ y2max, const float* __restrict__ y2min,
                    const float* __restrict__ wo, const float* __restrict__ g2, const float* __restrict__ b2,
                    float* stats, float* __restrict__ y3) {
    const int l = threadIdx.x & 63;
    const int wv = threadIdx.x >> 6;
    const int sidx = l & 15;
    const int g = l >> 4;
    const int ft = wv;

    unsigned int bh[2][4], bl[2][4];
    #pragma unroll
    for (int t = 0; t < 2; t++)
    #pragma unroll
    for (int r = 0; r < 4; r++) {
        int c0 = t*32 + g*8 + 2*r;
        split2(wo[c0*64 + ft*16 + sidx], wo[(c0+1)*64 + ft*16 + sidx], bh[t][r], bl[t][r]);
    }
    float sc2v[16], sh2v[16];
    const float inv = 1.0f / ((float)NPTS * (float)NS);
    #pragma unroll
    for (int t = 0; t < 2; t++)
    #pragma unroll
    for (int i = 0; i < 8; i++) {
        int c = t*32 + g*8 + i;
        float m = stats[SUM2 + c] * inv;
        float v = fmaxf(stats[SSQ2 + c] * inv - m*m, 0.0f);
        float s = g2[c] * rsqrtf(v + EPSV);
        sc2v[t*8+i] = s;
        sh2v[t*8+i] = fmaf(-m, s, b2[c]);
    }
    float s0a = 0.f, s1a = 0.f;
    for (int tile = blockIdx.x; tile < NPTS/16; tile += gridDim.x) {
        int p = tile*16 + sidx;
        unsigned int ahu[2][4], alu[2][4];
        #pragma unroll
        for (int t = 0; t < 2; t++) {
            f32x4 mx0 = *(const f32x4*)(y2max + (size_t)p*64 + t*32 + g*8);
            f32x4 mx1 = *(const f32x4*)(y2max + (size_t)p*64 + t*32 + g*8 + 4);
            f32x4 mn0 = *(const f32x4*)(y2min + (size_t)p*64 + t*32 + g*8);
            f32x4 mn1 = *(const f32x4*)(y2min + (size_t)p*64 + t*32 + g*8 + 4);
            float mval[8];
            #pragma unroll
            for (int i = 0; i < 4; i++) {
                float sc = sc2v[t*8+i];
                float pre = (sc >= 0.f) ? mx0[i] : mn0[i];
                mval[i] = fmaxf(fmaf(sc, pre, sh2v[t*8+i]), 0.0f);
                float sc2 = sc2v[t*8+4+i];
                float pre2 = (sc2 >= 0.f) ? mx1[i] : mn1[i];
                mval[4+i] = fmaxf(fmaf(sc2, pre2, sh2v[t*8+4+i]), 0.0f);
            }
            #pragma unroll
            for (int r = 0; r < 4; r++) split2(mval[2*r], mval[2*r+1], ahu[t][r], alu[t][r]);
        }
        f32x4 acc = (f32x4){0.f,0.f,0.f,0.f};
        #pragma unroll
        for (int t = 0; t < 2; t++) {
            FragU ah, al, Bh, Bl;
            ah.u = (u32x4){ahu[t][0], ahu[t][1], ahu[t][2], ahu[t][3]};
            al.u = (u32x4){alu[t][0], alu[t][1], alu[t][2], alu[t][3]};
            Bh.u = (u32x4){bh[t][0], bh[t][1], bh[t][2], bh[t][3]};
            Bl.u = (u32x4){bl[t][0], bl[t][1], bl[t][2], bl[t][3]};
            acc = __builtin_amdgcn_mfma_f32_16x16x32_bf16(ah.h, Bh.h, acc, 0, 0, 0);
            acc = __builtin_amdgcn_mfma_f32_16x16x32_bf16(ah.h, Bl.h, acc, 0, 0, 0);
            acc = __builtin_amdgcn_mfma_f32_16x16x32_bf16(al.h, Bh.h, acc, 0, 0, 0);
        }
        #pragma unroll
        for (int r = 0; r < 4; r++) {
            int po = tile*16 + g*4 + r;
            float v = acc[r];
            y3[(size_t)po*64 + ft*16 + sidx] = v;
            s0a += v;
            s1a = fmaf(v, v, s1a);
        }
    }
    s0a += __shfl_xor(s0a, 16, 64); s0a += __shfl_xor(s0a, 32, 64);
    s1a += __shfl_xor(s1a, 16, 64); s1a += __shfl_xor(s1a, 32, 64);
    __shared__ float r0[64], r1[64];
    if (l < 16) { r0[wv*16 + sidx] = s0a; r1[wv*16 + sidx] = s1a; }
    __syncthreads();
    int tid = threadIdx.x;
    if (tid < 64) {
        atomicAdd(&stats[SUM3 + tid], r0[tid]);
        atomicAdd(&stats[SSQ3 + tid], r1[tid]);
    }
}

// final: out = relu(bn3(y3)) in-place (layer 1 only).
__global__ void k6(float* y3, const float* stats, const float* go, const float* bo) {
    int i = blockIdx.x * 256 + threadIdx.x;
    int f = i & 63;
    const float inv = 1.0f / (float)NPTS;
    float m = stats[SUM3 + f] * inv;
    float v = fmaxf(stats[SSQ3 + f] * inv - m*m, 0.0f);
    float s = go[f] * rsqrtf(v + EPSV);
    float sh = fmaf(-m, s, bo[f]);
    y3[i] = fmaxf(fmaf(s, y3[i], sh), 0.0f);
}

extern "C" void kernel_launch(void* const* d_in, const int* in_sizes, int n_in,
                              void* d_out, int out_size, void* d_ws, size_t ws_size,
                              hipStream_t stream) {
    const float* xyz    = (const float*)d_in[0];
    const float* feats0 = (const float*)d_in[1];
    const int*   knn    = (const int*)d_in[2];
    const void*  empty  = d_in[3];
    float* ws = (float*)d_ws;
    const size_t N64 = (size_t)NPTS * 64;
    float* KA    = ws;
    float* QBA   = ws + N64;
    float* Y2MAX = ws + 2*N64;
    float* Y2MIN = ws + 3*N64;
    float* stats = ws + 4*N64;           // 2 x 512 floats
    float* wfold = stats + 1024;         // WFOLD_FLOATS
    uint8_t* mask = (uint8_t*)(wfold + WFOLD_FLOATS);
    float* out = (float*)d_out;

    hipMemsetAsync(stats, 0, 1024 * sizeof(float), stream);
    k_mask<<<NPTS/256, 256, 0, stream>>>((const uint32_t*)empty, mask);

    const float* const* p0 = (const float* const*)(d_in + 4);
    const float* const* p1 = (const float* const*)(d_in + 4 + 13);

    // ---- layer 0 ----
    {
        const float* const* p = p0;
        float* sl = stats;
        k0<<<16, 64, 0, stream>>>(p[0], p[1], p[2], p[3], p[4], wfold, 16);
        k1m<16, false><<<1024, 256, 0, stream>>>(feats0, xyz, p[4], wfold,
                                                 sl, p[11], p[12], KA, QBA);
        k2<<<2048, 256, 0, stream>>>(KA, QBA, knn, mask, sl);
        k4<<<2048, 256, 0, stream>>>(KA, QBA, knn, mask, p[7], p[5], p[6], sl, Y2MAX, Y2MIN);
        k5m<<<2048, 256, 0, stream>>>(Y2MAX, Y2MIN, p[10], p[8], p[9], sl, out);  // y3_0 -> d_out
    }
    // ---- layer 1 ----
    {
        const float* const* p = p1;
        float* sl = stats + 512;
        k0<<<64, 64, 0, stream>>>(p[0], p[1], p[2], p[3], p[4], wfold, 64);
        // PREBN: feats = relu(bn3_layer0(y3_0)) applied on the fly from d_out
        k1m<64, true><<<1024, 256, 0, stream>>>(out, xyz, p[4], wfold,
                                                stats, p0[11], p0[12], KA, QBA);
        k2<<<2048, 256, 0, stream>>>(KA, QBA, knn, mask, sl);
        k4<<<2048, 256, 0, stream>>>(KA, QBA, knn, mask, p[7], p[5], p[6], sl, Y2MAX, Y2MIN);
        k5m<<<2048, 256, 0, stream>>>(Y2MAX, Y2MIN, p[10], p[8], p[9], sl, out);  // y3_1 -> d_out
        k6<<<NPTS*64/256, 256, 0, stream>>>(out, sl, p[11], p[12]);               // in-place bn3
    }
}